// Round 7
// baseline (469.695 us; speedup 1.0000x reference)
//
#include <hip/hip_runtime.h>

#define Nn 100000
#define Ee 1600000
#define IND 256
#define HD 128
#define NCLS 40
#define NBLK 391   // ceil(Nn/256)

typedef _Float16 f16;
typedef f16 f16x8 __attribute__((ext_vector_type(8)));
typedef float f32x4 __attribute__((ext_vector_type(4)));

// Shared MFMA-tile macros (used by k_prep's hx branch and linkx_mlp).
// Free identifiers required at use site: lane, fh, mt, acc, rreg.
#define INIT_ACC(BIAS)                                                    \
    _Pragma("unroll")                                                     \
    for (int q = 0; q < 4; q++) {                                         \
        float bv = (BIAS)[(fh * 4 + q) * 16 + (lane & 15)];               \
        acc[q][0] = bv; acc[q][1] = bv; acc[q][2] = bv; acc[q][3] = bv;   \
    }

#define GEMM_K128(APACK, BP)                                                  \
    _Pragma("unroll")                                                         \
    for (int kt = 0; kt < 4; kt++) {                                          \
        f16x8 a = *(const f16x8*)((APACK) + ((mt * 4 + kt) * 64 + lane) * 8); \
        _Pragma("unroll")                                                     \
        for (int q = 0; q < 4; q++) {                                         \
            f16x8 b = *(const f16x8*)((BP) + (((fh*4+q)*4 + kt)*64 + lane)*8);\
            acc[q] = __builtin_amdgcn_mfma_f32_16x16x32_f16(a, b, acc[q], 0, 0, 0); \
        }                                                                     \
    }

// Epilogue -> packed LDS dst; MODE 0: relu, 2: no relu + rreg+=v,
// 3: h=relu(acc); v=relu(h+rreg)
#define EPILOGUE(MODE, PDST)                                                  \
    _Pragma("unroll")                                                         \
    for (int q = 0; q < 4; q++) {                                             \
        int f = (fh * 4 + q) * 16 + (lane & 15);                              \
        int kt2 = f >> 5, q2 = (f >> 3) & 3, j2 = f & 7;                      \
        _Pragma("unroll")                                                     \
        for (int r = 0; r < 4; r++) {                                         \
            int n = (lane >> 4) * 4 + r;                                      \
            float v = acc[q][r];                                              \
            if (MODE == 0) v = fmaxf(v, 0.f);                                 \
            if (MODE == 2) rreg[q][r] += v;                                   \
            if (MODE == 3) v = fmaxf(fmaxf(v, 0.f) + rreg[q][r], 0.f);        \
            (PDST)[((mt * 4 + kt2) * 64 + n + 16 * q2) * 8 + j2] = (f16)v;    \
        }                                                                     \
    }

// ---------------------------------------------------------------------------
// Standalone weight pack (runs BEFORE k_prep so its hx blocks can use wx1p/
// wx2p). P[((ft*KT+kt)*64+L)*8+j] = W[kt*32+(L>>4)*8+j][ft*16+(L&15)]
// ---------------------------------------------------------------------------
extern "C" __global__ void __launch_bounds__(256)
k_wpack(const float* __restrict__ wx1, const float* __restrict__ wx2,
        const float* __restrict__ wa1, const float* __restrict__ wa2,
        const float* __restrict__ ww1, const float* __restrict__ wc,
        f16* __restrict__ wp) {
    int idx = blockIdx.x * 256 + threadIdx.x;
    const float* W;
    int K, base;
    if (idx < 32768)       { W = wx1; K = 256; base = 0; }
    else if (idx < 49152)  { W = wx2; K = 128; base = 32768; }
    else if (idx < 65536)  { W = wa1; K = 128; base = 49152; }
    else if (idx < 81920)  { W = wa2; K = 128; base = 65536; }
    else if (idx < 114688) { W = ww1; K = 256; base = 81920; }
    else {
        // wc: [HD][NCLS] row-major, padded to 48 cols (3 ftiles), KT=4
        int local = idx - 114688;   // < 6144
        int j = local & 7;
        int L = (local >> 3) & 63;
        int kt = (local >> 9) & 3;
        int ft = local / 2048;
        int k = kt * 32 + (L >> 4) * 8 + j;
        int n = ft * 16 + (L & 15);
        wp[idx] = (n < NCLS) ? (f16)wc[k * NCLS + n] : (f16)0.f;
        return;
    }
    int local = idx - base;
    int KT = K >> 5;
    int j = local & 7;
    int L = (local >> 3) & 63;
    int kt = (local >> 9) % KT;
    int ft = local / (512 * KT);
    int k = kt * 32 + (L >> 4) * 8 + j;
    int n = ft * 16 + (L & 15);
    wp[idx] = (f16)W[k * HD + n];
}

// ---------------------------------------------------------------------------
// Fused prep, block-range partitioned to overlap the atomic-bound hist pass
// with streaming + MFMA work:
//   [0,1563)      hist-rank: 4 edges/thread, rank[e]=atomicAdd(&counts,1)
//   [1563,7813)   emb fp32->f16 (8 elems/thread).
//   [7813,10938)  hx branch (MLP steps 2-3) -> global hxp, A-frag packed.
// launch_bounds(256,4): VGPR budget 128 so the hx branch's u[16] hoist fits
// without spilling (R6 ran this kernel w/o min-waves: allocator chose 48
// VGPR and spilled ~48MB/iter -- WRITE_SIZE 106MB vs 58MB expected).
// ---------------------------------------------------------------------------
extern "C" __global__ void __launch_bounds__(256, 4)
k_prep(const int* __restrict__ ei, int* __restrict__ counts,
       int* __restrict__ rank,
       const float* __restrict__ emb, f16* __restrict__ embh,
       const float* __restrict__ x,
       const f16* __restrict__ wx1p, const float* __restrict__ bx1,
       const f16* __restrict__ wx2p, const float* __restrict__ bx2,
       f16* __restrict__ hxp) {
    __shared__ __align__(16) f16 pshr[4096];   // t1p for hx blocks (8KB)
    int bid = blockIdx.x;
    int t = threadIdx.x;
    if (bid < 1563) {
        int e0 = bid * 1024 + t;
#pragma unroll
        for (int k = 0; k < 4; k++) {
            int e = e0 + k * 256;
            if (e < Ee) {
                int dst = ei[Ee + e];
                rank[e] = atomicAdd(&counts[dst], 1);
            }
        }
        return;
    }
    if (bid < 7813) {
        int i = (bid - 1563) * 256 + t;
        const float4* pp = (const float4*)emb + (size_t)i * 2;
        float4 a = pp[0], b = pp[1];
        f16x8 h;
        h[0] = (f16)a.x; h[1] = (f16)a.y; h[2] = (f16)a.z; h[3] = (f16)a.w;
        h[4] = (f16)b.x; h[5] = (f16)b.y; h[6] = (f16)b.z; h[7] = (f16)b.w;
        *(f16x8*)(embh + (size_t)i * 8) = h;
        return;
    }
    // ---- hx branch: steps 2-3 of the MLP ----
    int unit = bid - 7813;              // 0..3124
    const int node0 = unit * 32;
    const int lane = t & 63;
    const int wid = t >> 6;
    const int mt = wid >> 1;
    const int fh = wid & 1;
    f32x4 acc[4];
    float rreg[4][4];                   // dummy for EPILOGUE macro
    (void)rreg;

    // step2: t1 = relu(x @ wx1 + bx1); 16 float4 x-loads hoisted for ILP
    INIT_ACC(bx1)
    {
        const float* xbase = x + (size_t)(node0 + mt * 16 + (lane & 15)) * IND
                               + (lane >> 4) * 8;
        float4 u[16];
#pragma unroll
        for (int kt = 0; kt < 8; kt++) {
            u[2 * kt]     = *(const float4*)(xbase + kt * 32);
            u[2 * kt + 1] = *(const float4*)(xbase + kt * 32 + 4);
        }
#pragma unroll
        for (int kt = 0; kt < 8; kt++) {
            float4 u0 = u[2 * kt], u1 = u[2 * kt + 1];
            f16x8 a;
            a[0] = (f16)u0.x; a[1] = (f16)u0.y; a[2] = (f16)u0.z; a[3] = (f16)u0.w;
            a[4] = (f16)u1.x; a[5] = (f16)u1.y; a[6] = (f16)u1.z; a[7] = (f16)u1.w;
#pragma unroll
            for (int q = 0; q < 4; q++) {
                f16x8 b = *(const f16x8*)(wx1p + (((fh*4+q)*8 + kt)*64 + lane)*8);
                acc[q] = __builtin_amdgcn_mfma_f32_16x16x32_f16(a, b, acc[q], 0, 0, 0);
            }
        }
    }
    EPILOGUE(0, pshr)         // t1p
    __syncthreads();

    // step3: hx = t1 @ wx2 + bx2 -> global hxp (packed, no relu)
    INIT_ACC(bx2)
    GEMM_K128(pshr, wx2p)
    {
        int gnt = unit * 2 + mt;
#pragma unroll
        for (int q = 0; q < 4; q++) {
            int f = (fh * 4 + q) * 16 + (lane & 15);
            int kt2 = f >> 5, q2 = (f >> 3) & 3, j2 = f & 7;
#pragma unroll
            for (int r = 0; r < 4; r++) {
                int n = (lane >> 4) * 4 + r;
                hxp[((gnt * 4 + kt2) * 64 + n + 16 * q2) * 8 + j2] = (f16)acc[q][r];
            }
        }
    }
}

extern "C" __global__ void __launch_bounds__(256)
k_scan1(const int* __restrict__ counts, int* __restrict__ bsum) {
    __shared__ int s[256];
    int t = threadIdx.x;
    int i = blockIdx.x * 256 + t;
    s[t] = (i < Nn) ? counts[i] : 0;
    __syncthreads();
    for (int d = 128; d > 0; d >>= 1) {
        if (t < d) s[t] += s[t + d];
        __syncthreads();
    }
    if (t == 0) bsum[blockIdx.x] = s[0];
}

// scan3 with fused scan2: each block reduces bsum[0..bid) itself (<=391 ints)
extern "C" __global__ void __launch_bounds__(256)
k_scan3(const int* __restrict__ counts, const int* __restrict__ bsum,
        int* __restrict__ offsets) {
    __shared__ int s[256];
    __shared__ int basev;
    int t = threadIdx.x;
    int i = blockIdx.x * 256 + t;
    int partial = 0;
    for (int k = t; k < blockIdx.x; k += 256) partial += bsum[k];
    s[t] = partial;
    __syncthreads();
    for (int d = 128; d > 0; d >>= 1) {
        if (t < d) s[t] += s[t + d];
        __syncthreads();
    }
    if (t == 0) basev = s[0];
    __syncthreads();
    int v = (i < Nn) ? counts[i] : 0;
    s[t] = v;
    __syncthreads();
    for (int d = 1; d < 256; d <<= 1) {
        int x = (t >= d) ? s[t - d] : 0;
        __syncthreads();
        s[t] += x;
        __syncthreads();
    }
    if (i < Nn) offsets[i] = basev + s[t] - v;
    if (i == 0) offsets[Nn] = Ee;
}

// pass 2: atomic-free scatter using precomputed ranks. bucket is written
// once and read once (k_gather) -> non-temporal store (no cache allocate).
extern "C" __global__ void __launch_bounds__(256)
k_scatter2(const int* __restrict__ ei, const int* __restrict__ offsets,
           const int* __restrict__ rank, int* __restrict__ bucket) {
    int e = blockIdx.x * 256 + threadIdx.x;
    int dst = ei[Ee + e];
    __builtin_nontemporal_store(ei[e], &bucket[offsets[dst] + rank[e]]);
}

// ---------------------------------------------------------------------------
// Gather-mean over f16 embeddings (unchanged): one wave per node,
// quarter-wave per edge slot, bucket preloaded + __shfl distribution.
// Output: MFMA A-frag packed layout.
// ---------------------------------------------------------------------------
extern "C" __global__ void __launch_bounds__(256)
k_gather(const int* __restrict__ offsets, const int* __restrict__ bucket,
         const f16* __restrict__ embh, f16* __restrict__ harawp) {
    int t = threadIdx.x;
    int lane = t & 63;
    int node = blockIdx.x * 4 + (t >> 6);
    int q = lane >> 4;
    int cl = (lane & 15) * 8;

    int beg = offsets[node];
    int end = offsets[node + 1];
    int deg = end - beg;

    int myidx = (lane < deg) ? bucket[beg + lane] : 0;

    float s[8];
#pragma unroll
    for (int j = 0; j < 8; j++) s[j] = 0.f;

    int dlim = (deg < 64) ? deg : 64;
    int e = q;
    for (; e + 4 < dlim; e += 8) {
        int a0 = __shfl(myidx, e);
        int a1 = __shfl(myidx, e + 4);
        f16x8 v0 = *(const f16x8*)(embh + (size_t)a0 * HD + cl);
        f16x8 v1 = *(const f16x8*)(embh + (size_t)a1 * HD + cl);
#pragma unroll
        for (int j = 0; j < 8; j++) s[j] += (float)v0[j] + (float)v1[j];
    }
    if (e < dlim) {
        int a0 = __shfl(myidx, e);
        f16x8 v0 = *(const f16x8*)(embh + (size_t)a0 * HD + cl);
#pragma unroll
        for (int j = 0; j < 8; j++) s[j] += (float)v0[j];
    }
    for (int i = beg + 64 + q; i < end; i += 4) {
        int a0 = bucket[i];
        f16x8 v0 = *(const f16x8*)(embh + (size_t)a0 * HD + cl);
#pragma unroll
        for (int j = 0; j < 8; j++) s[j] += (float)v0[j];
    }

#pragma unroll
    for (int j = 0; j < 8; j++) {
        s[j] += __shfl_down(s[j], 32);
        s[j] += __shfl_down(s[j], 16);
    }

    if (lane < 16) {
        float inv = 1.0f / fmaxf((float)deg, 1.0f);
        f16x8 h;
#pragma unroll
        for (int j = 0; j < 8; j++) h[j] = (f16)(s[j] * inv);
        int nt = node >> 4, m = node & 15;
        int kt = lane >> 2, q2 = lane & 3;
        *(f16x8*)(harawp + (((nt * 4 + kt) * 64 + m + 16 * q2) * 8)) = h;
    }
}

// ---------------------------------------------------------------------------
// MLP rest (steps 5-9). hx comes from global hxp (computed in k_prep).
// 32 nodes/block, 4 waves. LDS 16KB. launch_bounds(256,4): known-good.
// Tripwire: WRITE_SIZE must stay ~15.6MB (logits only); higher = spill.
// ---------------------------------------------------------------------------
extern "C" __global__ void __launch_bounds__(256, 4)
linkx_mlp(const f16* __restrict__ harawp, const f16* __restrict__ hxp,
          const f16* __restrict__ wa1p, const float* __restrict__ ba1,
          const f16* __restrict__ wa2p, const float* __restrict__ ba2,
          const f16* __restrict__ ww1p, const float* __restrict__ bw1,
          const f16* __restrict__ wcp, const float* __restrict__ bc,
          float* __restrict__ out) {
    __shared__ __align__(16) f16 shr[4096];   // t2p / h2p (8KB shared)
    __shared__ __align__(16) f16 hap[4096];   // ha packed (8KB)

    const int t = threadIdx.x;
    const int node0 = blockIdx.x * 32;
    const int lane = t & 63;
    const int wid = t >> 6;
    const int mt = wid >> 1;
    const int fh = wid & 1;
    const int gntb = (node0 >> 4) + mt;

    f32x4 acc[4];
    float rreg[4][4];

    // hx residual: 16 scalar f16 loads (L2/L3-hot), issued early
    f16 hxr[4][4];
#pragma unroll
    for (int q = 0; q < 4; q++) {
        int f = (fh * 4 + q) * 16 + (lane & 15);
        int kt2 = f >> 5, q2 = (f >> 3) & 3, j2 = f & 7;
#pragma unroll
        for (int r = 0; r < 4; r++) {
            int n = (lane >> 4) * 4 + r;
            hxr[q][r] = hxp[((gntb * 4 + kt2) * 64 + n + 16 * q2) * 8 + j2];
        }
    }

    // step5: t2 = relu(haraw @ wa1 + ba1); A hoisted from global packed f16
    INIT_ACC(ba1)
    {
        f16x8 av[4];
#pragma unroll
        for (int kt = 0; kt < 4; kt++)
            av[kt] = *(const f16x8*)(harawp + ((gntb * 4 + kt) * 64 + lane) * 8);
#pragma unroll
        for (int kt = 0; kt < 4; kt++) {
#pragma unroll
            for (int q = 0; q < 4; q++) {
                f16x8 b = *(const f16x8*)(wa1p + (((fh*4+q)*4 + kt)*64 + lane)*8);
                acc[q] = __builtin_amdgcn_mfma_f32_16x16x32_f16(av[kt], b, acc[q], 0, 0, 0);
            }
        }
    }
    EPILOGUE(0, shr)          // t2p
    __syncthreads();

    // rreg = hx
#pragma unroll
    for (int q = 0; q < 4; q++)
#pragma unroll
        for (int r = 0; r < 4; r++) rreg[q][r] = (float)hxr[q][r];

    // step6: ha = t2 @ wa2 + ba2 -> hap, rreg += ha
    INIT_ACC(ba2)
    GEMM_K128(shr, wa2p)
    EPILOGUE(2, hap)
    __syncthreads();          // t2p reads done -> shr reusable

    // step7+8: h2 = relu(relu([hx|ha] @ ww1 + bw1) + hx + ha) -> h2p
    INIT_ACC(bw1)
#pragma unroll
    for (int kt = 0; kt < 4; kt++) {   // hx half from GLOBAL hxp (coalesced)
        f16x8 a = *(const f16x8*)(hxp + ((gntb * 4 + kt) * 64 + lane) * 8);
#pragma unroll
        for (int q = 0; q < 4; q++) {
            f16x8 b = *(const f16x8*)(ww1p + (((fh*4+q)*8 + kt)*64 + lane)*8);
            acc[q] = __builtin_amdgcn_mfma_f32_16x16x32_f16(a, b, acc[q], 0, 0, 0);
        }
    }
#pragma unroll
    for (int kt = 4; kt < 8; kt++) {   // ha half from LDS
        f16x8 a = *(const f16x8*)(hap + ((mt * 4 + (kt - 4)) * 64 + lane) * 8);
#pragma unroll
        for (int q = 0; q < 4; q++) {
            f16x8 b = *(const f16x8*)(ww1p + (((fh*4+q)*8 + kt)*64 + lane)*8);
            acc[q] = __builtin_amdgcn_mfma_f32_16x16x32_f16(a, b, acc[q], 0, 0, 0);
        }
    }
    EPILOGUE(3, shr)          // h2p
    __syncthreads();

    // step9: logits = h2 @ wc + bc (3 ftiles: fh0 -> {0,2}, fh1 -> {1})
    {
        int nft = (fh == 0) ? 2 : 1;
#pragma unroll 2
        for (int ii = 0; ii < nft; ii++) {
            int ft = (ii == 0) ? fh : 2;
            int f = ft * 16 + (lane & 15);
            f32x4 c;
            float bv = (f < NCLS) ? bc[f] : 0.f;
            c[0] = bv; c[1] = bv; c[2] = bv; c[3] = bv;
#pragma unroll
            for (int kt = 0; kt < 4; kt++) {
                f16x8 a = *(const f16x8*)(shr + ((mt * 4 + kt) * 64 + lane) * 8);
                f16x8 b = *(const f16x8*)(wcp + ((ft * 4 + kt) * 64 + lane) * 8);
                c = __builtin_amdgcn_mfma_f32_16x16x32_f16(a, b, c, 0, 0, 0);
            }
            if (f < NCLS) {
#pragma unroll
                for (int r = 0; r < 4; r++) {
                    int n = node0 + mt * 16 + (lane >> 4) * 4 + r;
                    out[(size_t)n * NCLS + f] = c[r];
                }
            }
        }
    }
}

extern "C" void kernel_launch(void* const* d_in, const int* in_sizes, int n_in,
                              void* d_out, int out_size, void* d_ws, size_t ws_size,
                              hipStream_t stream) {
    const float* x   = (const float*)d_in[0];
    const int*   ei  = (const int*)d_in[1];
    const float* emb = (const float*)d_in[2];
    const float* wx1 = (const float*)d_in[3];
    const float* bx1 = (const float*)d_in[4];
    const float* wx2 = (const float*)d_in[5];
    const float* bx2 = (const float*)d_in[6];
    const float* wa1 = (const float*)d_in[7];
    const float* ba1 = (const float*)d_in[8];
    const float* wa2 = (const float*)d_in[9];
    const float* ba2 = (const float*)d_in[10];
    const float* ww1 = (const float*)d_in[11];
    const float* bw1 = (const float*)d_in[12];
    const float* wc  = (const float*)d_in[13];
    const float* bc  = (const float*)d_in[14];
    float* out = (float*)d_out;

    int* ws = (int*)d_ws;
    int* counts  = ws;                 // [Nn]  (atomic rank allocator)
    int* offsets = ws + 2 * Nn;        // [Nn+1]
    int* bsum    = ws + 3 * Nn + 16;   // [NBLK]
    int* bucket  = ws + 3 * Nn + 512;  // [Ee]
    f16* wp      = (f16*)(ws + 3 * Nn + 512 + Ee);  // 120832 f16 (16B aligned)
    f16* wx1p = wp;                 // 32768
    f16* wx2p = wp + 32768;         // 16384
    f16* wa1p = wp + 49152;         // 16384
    f16* wa2p = wp + 65536;         // 16384
    f16* ww1p = wp + 81920;         // 32768
    f16* wcp  = wp + 114688;        // 6144
    f16* harawp = wp + 131072;                       // [Nn*HD] f16, A-packed
    f16* embh   = harawp + (size_t)Nn * HD;          // [Nn*HD] f16, linear
    f16* hxp    = embh + (size_t)Nn * HD;            // [Nn*HD] f16, A-packed
    // rank[Ee] aliases harawp: rank is dead before k_gather writes harawp
    int* rank = (int*)harawp;

    hipMemsetAsync(ws, 0, (size_t)Nn * sizeof(int), stream);

    k_wpack<<<472, 256, 0, stream>>>(wx1, wx2, wa1, wa2, ww1, wc, wp);
    // [hist4: 1563][emb: 6250][hx: 3125] = 10938 blocks
    k_prep<<<10938, 256, 0, stream>>>(ei, counts, rank, emb, embh,
                                      x, wx1p, bx1, wx2p, bx2, hxp);
    k_scan1<<<NBLK, 256, 0, stream>>>(counts, bsum);
    k_scan3<<<NBLK, 256, 0, stream>>>(counts, bsum, offsets);
    k_scatter2<<<Ee / 256, 256, 0, stream>>>(ei, offsets, rank, bucket);
    k_gather<<<Nn / 4, 256, 0, stream>>>(offsets, bucket, embh, harawp);

    linkx_mlp<<<Nn / 32, 256, 0, stream>>>(harawp, hxp,
                                           wa1p, ba1, wa2p, ba2,
                                           ww1p, bw1, wcp, bc, out);
}

// Round 8
// 440.193 us; speedup vs baseline: 1.0670x; 1.0670x over previous
//
#include <hip/hip_runtime.h>

#define Nn 100000
#define Ee 1600000
#define IND 256
#define HD 128
#define NCLS 40
#define NBLK 391   // ceil(Nn/256)

typedef _Float16 f16;
typedef f16 f16x8 __attribute__((ext_vector_type(8)));
typedef float f32x4 __attribute__((ext_vector_type(4)));

// Shared MFMA-tile macros (used by k_prep's hx branch and linkx_mlp).
// Free identifiers required at use site: lane, fh, mt, acc, rreg.
#define INIT_ACC(BIAS)                                                    \
    _Pragma("unroll")                                                     \
    for (int q = 0; q < 4; q++) {                                         \
        float bv = (BIAS)[(fh * 4 + q) * 16 + (lane & 15)];               \
        acc[q][0] = bv; acc[q][1] = bv; acc[q][2] = bv; acc[q][3] = bv;   \
    }

#define GEMM_K128(APACK, BP)                                                  \
    _Pragma("unroll")                                                         \
    for (int kt = 0; kt < 4; kt++) {                                          \
        f16x8 a = *(const f16x8*)((APACK) + ((mt * 4 + kt) * 64 + lane) * 8); \
        _Pragma("unroll")                                                     \
        for (int q = 0; q < 4; q++) {                                         \
            f16x8 b = *(const f16x8*)((BP) + (((fh*4+q)*4 + kt)*64 + lane)*8);\
            acc[q] = __builtin_amdgcn_mfma_f32_16x16x32_f16(a, b, acc[q], 0, 0, 0); \
        }                                                                     \
    }

// Epilogue -> packed LDS dst; MODE 0: relu, 2: no relu + rreg+=v,
// 3: h=relu(acc); v=relu(h+rreg)
#define EPILOGUE(MODE, PDST)                                                  \
    _Pragma("unroll")                                                         \
    for (int q = 0; q < 4; q++) {                                             \
        int f = (fh * 4 + q) * 16 + (lane & 15);                              \
        int kt2 = f >> 5, q2 = (f >> 3) & 3, j2 = f & 7;                      \
        _Pragma("unroll")                                                     \
        for (int r = 0; r < 4; r++) {                                         \
            int n = (lane >> 4) * 4 + r;                                      \
            float v = acc[q][r];                                              \
            if (MODE == 0) v = fmaxf(v, 0.f);                                 \
            if (MODE == 2) rreg[q][r] += v;                                   \
            if (MODE == 3) v = fmaxf(fmaxf(v, 0.f) + rreg[q][r], 0.f);        \
            (PDST)[((mt * 4 + kt2) * 64 + n + 16 * q2) * 8 + j2] = (f16)v;    \
        }                                                                     \
    }

// ---------------------------------------------------------------------------
// Standalone weight pack (runs BEFORE k_prep so its hx blocks can use wx1p/
// wx2p). P[((ft*KT+kt)*64+L)*8+j] = W[kt*32+(L>>4)*8+j][ft*16+(L&15)]
// ---------------------------------------------------------------------------
extern "C" __global__ void __launch_bounds__(256)
k_wpack(const float* __restrict__ wx1, const float* __restrict__ wx2,
        const float* __restrict__ wa1, const float* __restrict__ wa2,
        const float* __restrict__ ww1, const float* __restrict__ wc,
        f16* __restrict__ wp) {
    int idx = blockIdx.x * 256 + threadIdx.x;
    const float* W;
    int K, base;
    if (idx < 32768)       { W = wx1; K = 256; base = 0; }
    else if (idx < 49152)  { W = wx2; K = 128; base = 32768; }
    else if (idx < 65536)  { W = wa1; K = 128; base = 49152; }
    else if (idx < 81920)  { W = wa2; K = 128; base = 65536; }
    else if (idx < 114688) { W = ww1; K = 256; base = 81920; }
    else {
        // wc: [HD][NCLS] row-major, padded to 48 cols (3 ftiles), KT=4
        int local = idx - 114688;   // < 6144
        int j = local & 7;
        int L = (local >> 3) & 63;
        int kt = (local >> 9) & 3;
        int ft = local / 2048;
        int k = kt * 32 + (L >> 4) * 8 + j;
        int n = ft * 16 + (L & 15);
        wp[idx] = (n < NCLS) ? (f16)wc[k * NCLS + n] : (f16)0.f;
        return;
    }
    int local = idx - base;
    int KT = K >> 5;
    int j = local & 7;
    int L = (local >> 3) & 63;
    int kt = (local >> 9) % KT;
    int ft = local / (512 * KT);
    int k = kt * 32 + (L >> 4) * 8 + j;
    int n = ft * 16 + (L & 15);
    wp[idx] = (f16)W[k * HD + n];
}

// ---------------------------------------------------------------------------
// Fused prep. Three phases INTERLEAVED mod-7 (1 hist : 4 emb : 2 hx per
// group) so atomic-latency-bound, BW-bound and MFMA-bound blocks coexist on
// every CU for the whole kernel (R5-R7 used contiguous ranges -> phases ran
// sequentially, no overlap).
//   hist (1563 units): 4 edges/thread, rank[e]=atomicAdd(&counts[dst],1)
//   emb  (6250 units): emb fp32->f16, 8 elems/thread
//   hx   (3125 units): MLP steps 2-3 -> global hxp, A-frag packed
// amdgpu_waves_per_eu(4,4): sets the allocator's occupancy TARGET (max),
// not just a floor -> up to 128 VGPR, so the hx u[16] hoist stays in
// registers. (launch_bounds(256,4) only sets the min: R7 still chose 44
// VGPR via its occupancy heuristic and the hx x-loads serialized.)
// ---------------------------------------------------------------------------
extern "C" __global__
__attribute__((amdgpu_flat_work_group_size(256, 256), amdgpu_waves_per_eu(4, 4)))
void k_prep(const int* __restrict__ ei, int* __restrict__ counts,
            int* __restrict__ rank,
            const float* __restrict__ emb, f16* __restrict__ embh,
            const float* __restrict__ x,
            const f16* __restrict__ wx1p, const float* __restrict__ bx1,
            const f16* __restrict__ wx2p, const float* __restrict__ bx2,
            f16* __restrict__ hxp) {
    __shared__ __align__(16) f16 pshr[4096];   // t1p for hx blocks (8KB)
    int bid = blockIdx.x;
    int t = threadIdx.x;

    // block -> (phase, unit) interleave: groups of 7 = [1 hist|4 emb|2 hx]
    int kind, p;
    if (bid < 10934) {
        int g = bid / 7, r = bid - g * 7;
        if (r == 0)      { kind = 0; p = g; }
        else if (r <= 4) { kind = 1; p = g * 4 + (r - 1); }
        else             { kind = 2; p = g * 2 + (r - 5); }
    } else {
        int r = bid - 10934;        // 0..3 -> [hist, emb, emb, hx]
        if (r == 0)      { kind = 0; p = 1562; }
        else if (r <= 2) { kind = 1; p = 6248 + (r - 1); }
        else             { kind = 2; p = 3124; }
    }

    if (kind == 0) {
        int e0 = p * 1024 + t;
#pragma unroll
        for (int k = 0; k < 4; k++) {
            int e = e0 + k * 256;
            if (e < Ee) {
                int dst = ei[Ee + e];
                rank[e] = atomicAdd(&counts[dst], 1);
            }
        }
        return;
    }
    if (kind == 1) {
        int i = p * 256 + t;
        const float4* pp = (const float4*)emb + (size_t)i * 2;
        float4 a = pp[0], b = pp[1];
        f16x8 h;
        h[0] = (f16)a.x; h[1] = (f16)a.y; h[2] = (f16)a.z; h[3] = (f16)a.w;
        h[4] = (f16)b.x; h[5] = (f16)b.y; h[6] = (f16)b.z; h[7] = (f16)b.w;
        *(f16x8*)(embh + (size_t)i * 8) = h;
        return;
    }
    // ---- hx branch: steps 2-3 of the MLP ----
    int unit = p;                       // 0..3124
    const int node0 = unit * 32;
    const int lane = t & 63;
    const int wid = t >> 6;
    const int mt = wid >> 1;
    const int fh = wid & 1;
    f32x4 acc[4];
    float rreg[4][4];                   // dummy for EPILOGUE macro
    (void)rreg;

    // step2: t1 = relu(x @ wx1 + bx1); 16 float4 x-loads hoisted for ILP
    INIT_ACC(bx1)
    {
        const float* xbase = x + (size_t)(node0 + mt * 16 + (lane & 15)) * IND
                               + (lane >> 4) * 8;
        float4 u[16];
#pragma unroll
        for (int kt = 0; kt < 8; kt++) {
            u[2 * kt]     = *(const float4*)(xbase + kt * 32);
            u[2 * kt + 1] = *(const float4*)(xbase + kt * 32 + 4);
        }
#pragma unroll
        for (int kt = 0; kt < 8; kt++) {
            float4 u0 = u[2 * kt], u1 = u[2 * kt + 1];
            f16x8 a;
            a[0] = (f16)u0.x; a[1] = (f16)u0.y; a[2] = (f16)u0.z; a[3] = (f16)u0.w;
            a[4] = (f16)u1.x; a[5] = (f16)u1.y; a[6] = (f16)u1.z; a[7] = (f16)u1.w;
#pragma unroll
            for (int q = 0; q < 4; q++) {
                f16x8 b = *(const f16x8*)(wx1p + (((fh*4+q)*8 + kt)*64 + lane)*8);
                acc[q] = __builtin_amdgcn_mfma_f32_16x16x32_f16(a, b, acc[q], 0, 0, 0);
            }
        }
    }
    EPILOGUE(0, pshr)         // t1p
    __syncthreads();

    // step3: hx = t1 @ wx2 + bx2 -> global hxp (packed, no relu)
    INIT_ACC(bx2)
    GEMM_K128(pshr, wx2p)
    {
        int gnt = unit * 2 + mt;
#pragma unroll
        for (int q = 0; q < 4; q++) {
            int f = (fh * 4 + q) * 16 + (lane & 15);
            int kt2 = f >> 5, q2 = (f >> 3) & 3, j2 = f & 7;
#pragma unroll
            for (int r = 0; r < 4; r++) {
                int n = (lane >> 4) * 4 + r;
                hxp[((gnt * 4 + kt2) * 64 + n + 16 * q2) * 8 + j2] = (f16)acc[q][r];
            }
        }
    }
}

extern "C" __global__ void __launch_bounds__(256)
k_scan1(const int* __restrict__ counts, int* __restrict__ bsum) {
    __shared__ int s[256];
    int t = threadIdx.x;
    int i = blockIdx.x * 256 + t;
    s[t] = (i < Nn) ? counts[i] : 0;
    __syncthreads();
    for (int d = 128; d > 0; d >>= 1) {
        if (t < d) s[t] += s[t + d];
        __syncthreads();
    }
    if (t == 0) bsum[blockIdx.x] = s[0];
}

// scan3 with fused scan2: each block reduces bsum[0..bid) itself (<=391 ints)
extern "C" __global__ void __launch_bounds__(256)
k_scan3(const int* __restrict__ counts, const int* __restrict__ bsum,
        int* __restrict__ offsets) {
    __shared__ int s[256];
    __shared__ int basev;
    int t = threadIdx.x;
    int i = blockIdx.x * 256 + t;
    int partial = 0;
    for (int k = t; k < blockIdx.x; k += 256) partial += bsum[k];
    s[t] = partial;
    __syncthreads();
    for (int d = 128; d > 0; d >>= 1) {
        if (t < d) s[t] += s[t + d];
        __syncthreads();
    }
    if (t == 0) basev = s[0];
    __syncthreads();
    int v = (i < Nn) ? counts[i] : 0;
    s[t] = v;
    __syncthreads();
    for (int d = 1; d < 256; d <<= 1) {
        int x = (t >= d) ? s[t - d] : 0;
        __syncthreads();
        s[t] += x;
        __syncthreads();
    }
    if (i < Nn) offsets[i] = basev + s[t] - v;
    if (i == 0) offsets[Nn] = Ee;
}

// pass 2: atomic-free scatter using precomputed ranks. bucket is written
// once and read once (k_gather) -> non-temporal store (no cache allocate).
extern "C" __global__ void __launch_bounds__(256)
k_scatter2(const int* __restrict__ ei, const int* __restrict__ offsets,
           const int* __restrict__ rank, int* __restrict__ bucket) {
    int e = blockIdx.x * 256 + threadIdx.x;
    int dst = ei[Ee + e];
    __builtin_nontemporal_store(ei[e], &bucket[offsets[dst] + rank[e]]);
}

// ---------------------------------------------------------------------------
// Gather-mean over f16 embeddings (unchanged): one wave per node,
// quarter-wave per edge slot, bucket preloaded + __shfl distribution.
// Output: MFMA A-frag packed layout.
// ---------------------------------------------------------------------------
extern "C" __global__ void __launch_bounds__(256)
k_gather(const int* __restrict__ offsets, const int* __restrict__ bucket,
         const f16* __restrict__ embh, f16* __restrict__ harawp) {
    int t = threadIdx.x;
    int lane = t & 63;
    int node = blockIdx.x * 4 + (t >> 6);
    int q = lane >> 4;
    int cl = (lane & 15) * 8;

    int beg = offsets[node];
    int end = offsets[node + 1];
    int deg = end - beg;

    int myidx = (lane < deg) ? bucket[beg + lane] : 0;

    float s[8];
#pragma unroll
    for (int j = 0; j < 8; j++) s[j] = 0.f;

    int dlim = (deg < 64) ? deg : 64;
    int e = q;
    for (; e + 4 < dlim; e += 8) {
        int a0 = __shfl(myidx, e);
        int a1 = __shfl(myidx, e + 4);
        f16x8 v0 = *(const f16x8*)(embh + (size_t)a0 * HD + cl);
        f16x8 v1 = *(const f16x8*)(embh + (size_t)a1 * HD + cl);
#pragma unroll
        for (int j = 0; j < 8; j++) s[j] += (float)v0[j] + (float)v1[j];
    }
    if (e < dlim) {
        int a0 = __shfl(myidx, e);
        f16x8 v0 = *(const f16x8*)(embh + (size_t)a0 * HD + cl);
#pragma unroll
        for (int j = 0; j < 8; j++) s[j] += (float)v0[j];
    }
    for (int i = beg + 64 + q; i < end; i += 4) {
        int a0 = bucket[i];
        f16x8 v0 = *(const f16x8*)(embh + (size_t)a0 * HD + cl);
#pragma unroll
        for (int j = 0; j < 8; j++) s[j] += (float)v0[j];
    }

#pragma unroll
    for (int j = 0; j < 8; j++) {
        s[j] += __shfl_down(s[j], 32);
        s[j] += __shfl_down(s[j], 16);
    }

    if (lane < 16) {
        float inv = 1.0f / fmaxf((float)deg, 1.0f);
        f16x8 h;
#pragma unroll
        for (int j = 0; j < 8; j++) h[j] = (f16)(s[j] * inv);
        int nt = node >> 4, m = node & 15;
        int kt = lane >> 2, q2 = lane & 3;
        *(f16x8*)(harawp + (((nt * 4 + kt) * 64 + m + 16 * q2) * 8)) = h;
    }
}

// ---------------------------------------------------------------------------
// MLP rest (steps 5-9). hx comes from global hxp (computed in k_prep).
// 32 nodes/block, 4 waves. LDS 16KB. launch_bounds(256,4): known-good.
// Tripwire: WRITE_SIZE must stay ~15.6MB (logits only); higher = spill.
// ---------------------------------------------------------------------------
extern "C" __global__ void __launch_bounds__(256, 4)
linkx_mlp(const f16* __restrict__ harawp, const f16* __restrict__ hxp,
          const f16* __restrict__ wa1p, const float* __restrict__ ba1,
          const f16* __restrict__ wa2p, const float* __restrict__ ba2,
          const f16* __restrict__ ww1p, const float* __restrict__ bw1,
          const f16* __restrict__ wcp, const float* __restrict__ bc,
          float* __restrict__ out) {
    __shared__ __align__(16) f16 shr[4096];   // t2p / h2p (8KB shared)
    __shared__ __align__(16) f16 hap[4096];   // ha packed (8KB)

    const int t = threadIdx.x;
    const int node0 = blockIdx.x * 32;
    const int lane = t & 63;
    const int wid = t >> 6;
    const int mt = wid >> 1;
    const int fh = wid & 1;
    const int gntb = (node0 >> 4) + mt;

    f32x4 acc[4];
    float rreg[4][4];

    // hx residual: 16 scalar f16 loads (L2/L3-hot), issued early
    f16 hxr[4][4];
#pragma unroll
    for (int q = 0; q < 4; q++) {
        int f = (fh * 4 + q) * 16 + (lane & 15);
        int kt2 = f >> 5, q2 = (f >> 3) & 3, j2 = f & 7;
#pragma unroll
        for (int r = 0; r < 4; r++) {
            int n = (lane >> 4) * 4 + r;
            hxr[q][r] = hxp[((gntb * 4 + kt2) * 64 + n + 16 * q2) * 8 + j2];
        }
    }

    // step5: t2 = relu(haraw @ wa1 + ba1); A hoisted from global packed f16
    INIT_ACC(ba1)
    {
        f16x8 av[4];
#pragma unroll
        for (int kt = 0; kt < 4; kt++)
            av[kt] = *(const f16x8*)(harawp + ((gntb * 4 + kt) * 64 + lane) * 8);
#pragma unroll
        for (int kt = 0; kt < 4; kt++) {
#pragma unroll
            for (int q = 0; q < 4; q++) {
                f16x8 b = *(const f16x8*)(wa1p + (((fh*4+q)*4 + kt)*64 + lane)*8);
                acc[q] = __builtin_amdgcn_mfma_f32_16x16x32_f16(av[kt], b, acc[q], 0, 0, 0);
            }
        }
    }
    EPILOGUE(0, shr)          // t2p
    __syncthreads();

    // rreg = hx
#pragma unroll
    for (int q = 0; q < 4; q++)
#pragma unroll
        for (int r = 0; r < 4; r++) rreg[q][r] = (float)hxr[q][r];

    // step6: ha = t2 @ wa2 + ba2 -> hap, rreg += ha
    INIT_ACC(ba2)
    GEMM_K128(shr, wa2p)
    EPILOGUE(2, hap)
    __syncthreads();          // t2p reads done -> shr reusable

    // step7+8: h2 = relu(relu([hx|ha] @ ww1 + bw1) + hx + ha) -> h2p
    INIT_ACC(bw1)
#pragma unroll
    for (int kt = 0; kt < 4; kt++) {   // hx half from GLOBAL hxp (coalesced)
        f16x8 a = *(const f16x8*)(hxp + ((gntb * 4 + kt) * 64 + lane) * 8);
#pragma unroll
        for (int q = 0; q < 4; q++) {
            f16x8 b = *(const f16x8*)(ww1p + (((fh*4+q)*8 + kt)*64 + lane)*8);
            acc[q] = __builtin_amdgcn_mfma_f32_16x16x32_f16(a, b, acc[q], 0, 0, 0);
        }
    }
#pragma unroll
    for (int kt = 4; kt < 8; kt++) {   // ha half from LDS
        f16x8 a = *(const f16x8*)(hap + ((mt * 4 + (kt - 4)) * 64 + lane) * 8);
#pragma unroll
        for (int q = 0; q < 4; q++) {
            f16x8 b = *(const f16x8*)(ww1p + (((fh*4+q)*8 + kt)*64 + lane)*8);
            acc[q] = __builtin_amdgcn_mfma_f32_16x16x32_f16(a, b, acc[q], 0, 0, 0);
        }
    }
    EPILOGUE(3, shr)          // h2p
    __syncthreads();

    // step9: logits = h2 @ wc + bc (3 ftiles: fh0 -> {0,2}, fh1 -> {1})
    {
        int nft = (fh == 0) ? 2 : 1;
#pragma unroll 2
        for (int ii = 0; ii < nft; ii++) {
            int ft = (ii == 0) ? fh : 2;
            int f = ft * 16 + (lane & 15);
            f32x4 c;
            float bv = (f < NCLS) ? bc[f] : 0.f;
            c[0] = bv; c[1] = bv; c[2] = bv; c[3] = bv;
#pragma unroll
            for (int kt = 0; kt < 4; kt++) {
                f16x8 a = *(const f16x8*)(shr + ((mt * 4 + kt) * 64 + lane) * 8);
                f16x8 b = *(const f16x8*)(wcp + ((ft * 4 + kt) * 64 + lane) * 8);
                c = __builtin_amdgcn_mfma_f32_16x16x32_f16(a, b, c, 0, 0, 0);
            }
            if (f < NCLS) {
#pragma unroll
                for (int r = 0; r < 4; r++) {
                    int n = node0 + mt * 16 + (lane >> 4) * 4 + r;
                    out[(size_t)n * NCLS + f] = c[r];
                }
            }
        }
    }
}

extern "C" void kernel_launch(void* const* d_in, const int* in_sizes, int n_in,
                              void* d_out, int out_size, void* d_ws, size_t ws_size,
                              hipStream_t stream) {
    const float* x   = (const float*)d_in[0];
    const int*   ei  = (const int*)d_in[1];
    const float* emb = (const float*)d_in[2];
    const float* wx1 = (const float*)d_in[3];
    const float* bx1 = (const float*)d_in[4];
    const float* wx2 = (const float*)d_in[5];
    const float* bx2 = (const float*)d_in[6];
    const float* wa1 = (const float*)d_in[7];
    const float* ba1 = (const float*)d_in[8];
    const float* wa2 = (const float*)d_in[9];
    const float* ba2 = (const float*)d_in[10];
    const float* ww1 = (const float*)d_in[11];
    const float* bw1 = (const float*)d_in[12];
    const float* wc  = (const float*)d_in[13];
    const float* bc  = (const float*)d_in[14];
    float* out = (float*)d_out;

    int* ws = (int*)d_ws;
    int* counts  = ws;                 // [Nn]  (atomic rank allocator)
    int* offsets = ws + 2 * Nn;        // [Nn+1]
    int* bsum    = ws + 3 * Nn + 16;   // [NBLK]
    int* bucket  = ws + 3 * Nn + 512;  // [Ee]
    f16* wp      = (f16*)(ws + 3 * Nn + 512 + Ee);  // 120832 f16 (16B aligned)
    f16* wx1p = wp;                 // 32768
    f16* wx2p = wp + 32768;         // 16384
    f16* wa1p = wp + 49152;         // 16384
    f16* wa2p = wp + 65536;         // 16384
    f16* ww1p = wp + 81920;         // 32768
    f16* wcp  = wp + 114688;        // 6144
    f16* harawp = wp + 131072;                       // [Nn*HD] f16, A-packed
    f16* embh   = harawp + (size_t)Nn * HD;          // [Nn*HD] f16, linear
    f16* hxp    = embh + (size_t)Nn * HD;            // [Nn*HD] f16, A-packed
    // rank[Ee] aliases harawp: rank is dead before k_gather writes harawp
    int* rank = (int*)harawp;

    hipMemsetAsync(ws, 0, (size_t)Nn * sizeof(int), stream);

    k_wpack<<<472, 256, 0, stream>>>(wx1, wx2, wa1, wa2, ww1, wc, wp);
    // 10938 blocks = interleaved [1 hist | 4 emb | 2 hx] groups of 7
    k_prep<<<10938, 256, 0, stream>>>(ei, counts, rank, emb, embh,
                                      x, wx1p, bx1, wx2p, bx2, hxp);
    k_scan1<<<NBLK, 256, 0, stream>>>(counts, bsum);
    k_scan3<<<NBLK, 256, 0, stream>>>(counts, bsum, offsets);
    k_scatter2<<<Ee / 256, 256, 0, stream>>>(ei, offsets, rank, bucket);
    k_gather<<<Nn / 4, 256, 0, stream>>>(offsets, bucket, embh, harawp);

    linkx_mlp<<<Nn / 32, 256, 0, stream>>>(harawp, hxp,
                                           wa1p, ba1, wa2p, ba2,
                                           ww1p, bw1, wcp, bc, out);
}

// Round 9
// 426.859 us; speedup vs baseline: 1.1004x; 1.0312x over previous
//
#include <hip/hip_runtime.h>

#define Nn 100000
#define Ee 1600000
#define IND 256
#define HD 128
#define NCLS 40
#define NBLK 391   // ceil(Nn/256)

typedef _Float16 f16;
typedef f16 f16x8 __attribute__((ext_vector_type(8)));
typedef float f32x4 __attribute__((ext_vector_type(4)));

// Shared MFMA-tile macros. Free identifiers at use site: lane, fh, mt, acc, rreg.
#define INIT_ACC(BIAS)                                                    \
    _Pragma("unroll")                                                     \
    for (int q = 0; q < 4; q++) {                                         \
        float bv = (BIAS)[(fh * 4 + q) * 16 + (lane & 15)];               \
        acc[q][0] = bv; acc[q][1] = bv; acc[q][2] = bv; acc[q][3] = bv;   \
    }

#define GEMM_K128(APACK, BP)                                                  \
    _Pragma("unroll")                                                         \
    for (int kt = 0; kt < 4; kt++) {                                          \
        f16x8 a = *(const f16x8*)((APACK) + ((mt * 4 + kt) * 64 + lane) * 8); \
        _Pragma("unroll")                                                     \
        for (int q = 0; q < 4; q++) {                                         \
            f16x8 b = *(const f16x8*)((BP) + (((fh*4+q)*4 + kt)*64 + lane)*8);\
            acc[q] = __builtin_amdgcn_mfma_f32_16x16x32_f16(a, b, acc[q], 0, 0, 0); \
        }                                                                     \
    }

// Epilogue -> packed LDS dst; MODE 0: relu, 2: no relu + rreg+=v,
// 3: h=relu(acc); v=relu(h+rreg)
#define EPILOGUE(MODE, PDST)                                                  \
    _Pragma("unroll")                                                         \
    for (int q = 0; q < 4; q++) {                                             \
        int f = (fh * 4 + q) * 16 + (lane & 15);                              \
        int kt2 = f >> 5, q2 = (f >> 3) & 3, j2 = f & 7;                      \
        _Pragma("unroll")                                                     \
        for (int r = 0; r < 4; r++) {                                         \
            int n = (lane >> 4) * 4 + r;                                      \
            float v = acc[q][r];                                              \
            if (MODE == 0) v = fmaxf(v, 0.f);                                 \
            if (MODE == 2) rreg[q][r] += v;                                   \
            if (MODE == 3) v = fmaxf(fmaxf(v, 0.f) + rreg[q][r], 0.f);        \
            (PDST)[((mt * 4 + kt2) * 64 + n + 16 * q2) * 8 + j2] = (f16)v;    \
        }                                                                     \
    }

// ---------------------------------------------------------------------------
// Standalone weight pack (runs BEFORE k_prep so its hx blocks can use wx1p/
// wx2p). P[((ft*KT+kt)*64+L)*8+j] = W[kt*32+(L>>4)*8+j][ft*16+(L&15)]
// ---------------------------------------------------------------------------
extern "C" __global__ void __launch_bounds__(256)
k_wpack(const float* __restrict__ wx1, const float* __restrict__ wx2,
        const float* __restrict__ wa1, const float* __restrict__ wa2,
        const float* __restrict__ ww1, const float* __restrict__ wc,
        f16* __restrict__ wp) {
    int idx = blockIdx.x * 256 + threadIdx.x;
    const float* W;
    int K, base;
    if (idx < 32768)       { W = wx1; K = 256; base = 0; }
    else if (idx < 49152)  { W = wx2; K = 128; base = 32768; }
    else if (idx < 65536)  { W = wa1; K = 128; base = 49152; }
    else if (idx < 81920)  { W = wa2; K = 128; base = 65536; }
    else if (idx < 114688) { W = ww1; K = 256; base = 81920; }
    else {
        // wc: [HD][NCLS] row-major, padded to 48 cols (3 ftiles), KT=4
        int local = idx - 114688;   // < 6144
        int j = local & 7;
        int L = (local >> 3) & 63;
        int kt = (local >> 9) & 3;
        int ft = local / 2048;
        int k = kt * 32 + (L >> 4) * 8 + j;
        int n = ft * 16 + (L & 15);
        wp[idx] = (n < NCLS) ? (f16)wc[k * NCLS + n] : (f16)0.f;
        return;
    }
    int local = idx - base;
    int KT = K >> 5;
    int j = local & 7;
    int L = (local >> 3) & 63;
    int kt = (local >> 9) % KT;
    int ft = local / (512 * KT);
    int k = kt * 32 + (L >> 4) * 8 + j;
    int n = ft * 16 + (L & 15);
    wp[idx] = (f16)W[k * HD + n];
}

// ---------------------------------------------------------------------------
// Fused prep. Phases INTERLEAVED mod-7 (1 hist : 4 emb : 2 hx per group) so
// atomic-latency-bound, BW-bound and MFMA-bound blocks coexist on every CU.
//   hist (1563 units): 4 edges/thread, rank[e]=atomicAdd(&counts[dst],1)
//   emb  (6250 units): emb fp32->f16, 8 elems/thread
//   hx   (3125 units): MLP steps 2-3 -> global hxp, A-frag packed
// Plain launch_bounds(256): R8's amdgpu_waves_per_eu(4,4) CAPPED occupancy
// at 38% without raising VGPR (52) -- the hist phase wants max waves.
// WRITE_SIZE note: ~106MB = 57.6MB real + ~48.6MB atomic-RMW accounting
// (byte-identical across 44/48/52-VGPR builds -> NOT spill).
// ---------------------------------------------------------------------------
extern "C" __global__ void __launch_bounds__(256)
k_prep(const int* __restrict__ ei, int* __restrict__ counts,
       int* __restrict__ rank,
       const float* __restrict__ emb, f16* __restrict__ embh,
       const float* __restrict__ x,
       const f16* __restrict__ wx1p, const float* __restrict__ bx1,
       const f16* __restrict__ wx2p, const float* __restrict__ bx2,
       f16* __restrict__ hxp) {
    __shared__ __align__(16) f16 pshr[4096];   // t1p for hx blocks (8KB)
    int bid = blockIdx.x;
    int t = threadIdx.x;

    // block -> (phase, unit) interleave: groups of 7 = [1 hist|4 emb|2 hx]
    int kind, p;
    if (bid < 10934) {
        int g = bid / 7, r = bid - g * 7;
        if (r == 0)      { kind = 0; p = g; }
        else if (r <= 4) { kind = 1; p = g * 4 + (r - 1); }
        else             { kind = 2; p = g * 2 + (r - 5); }
    } else {
        int r = bid - 10934;        // 0..3 -> [hist, emb, emb, hx]
        if (r == 0)      { kind = 0; p = 1562; }
        else if (r <= 2) { kind = 1; p = 6248 + (r - 1); }
        else             { kind = 2; p = 3124; }
    }

    if (kind == 0) {
        int e0 = p * 1024 + t;
#pragma unroll
        for (int k = 0; k < 4; k++) {
            int e = e0 + k * 256;
            if (e < Ee) {
                int dst = ei[Ee + e];
                rank[e] = atomicAdd(&counts[dst], 1);
            }
        }
        return;
    }
    if (kind == 1) {
        int i = p * 256 + t;
        const float4* pp = (const float4*)emb + (size_t)i * 2;
        float4 a = pp[0], b = pp[1];
        f16x8 h;
        h[0] = (f16)a.x; h[1] = (f16)a.y; h[2] = (f16)a.z; h[3] = (f16)a.w;
        h[4] = (f16)b.x; h[5] = (f16)b.y; h[6] = (f16)b.z; h[7] = (f16)b.w;
        *(f16x8*)(embh + (size_t)i * 8) = h;
        return;
    }
    // ---- hx branch: steps 2-3 of the MLP ----
    int unit = p;                       // 0..3124
    const int node0 = unit * 32;
    const int lane = t & 63;
    const int wid = t >> 6;
    const int mt = wid >> 1;
    const int fh = wid & 1;
    f32x4 acc[4];
    float rreg[4][4];                   // dummy for EPILOGUE macro
    (void)rreg;

    // step2: t1 = relu(x @ wx1 + bx1); 16 float4 x-loads hoisted for ILP
    INIT_ACC(bx1)
    {
        const float* xbase = x + (size_t)(node0 + mt * 16 + (lane & 15)) * IND
                               + (lane >> 4) * 8;
        float4 u[16];
#pragma unroll
        for (int kt = 0; kt < 8; kt++) {
            u[2 * kt]     = *(const float4*)(xbase + kt * 32);
            u[2 * kt + 1] = *(const float4*)(xbase + kt * 32 + 4);
        }
#pragma unroll
        for (int kt = 0; kt < 8; kt++) {
            float4 u0 = u[2 * kt], u1 = u[2 * kt + 1];
            f16x8 a;
            a[0] = (f16)u0.x; a[1] = (f16)u0.y; a[2] = (f16)u0.z; a[3] = (f16)u0.w;
            a[4] = (f16)u1.x; a[5] = (f16)u1.y; a[6] = (f16)u1.z; a[7] = (f16)u1.w;
#pragma unroll
            for (int q = 0; q < 4; q++) {
                f16x8 b = *(const f16x8*)(wx1p + (((fh*4+q)*8 + kt)*64 + lane)*8);
                acc[q] = __builtin_amdgcn_mfma_f32_16x16x32_f16(a, b, acc[q], 0, 0, 0);
            }
        }
    }
    EPILOGUE(0, pshr)         // t1p
    __syncthreads();

    // step3: hx = t1 @ wx2 + bx2 -> global hxp (packed, no relu)
    INIT_ACC(bx2)
    GEMM_K128(pshr, wx2p)
    {
        int gnt = unit * 2 + mt;
#pragma unroll
        for (int q = 0; q < 4; q++) {
            int f = (fh * 4 + q) * 16 + (lane & 15);
            int kt2 = f >> 5, q2 = (f >> 3) & 3, j2 = f & 7;
#pragma unroll
            for (int r = 0; r < 4; r++) {
                int n = (lane >> 4) * 4 + r;
                hxp[((gnt * 4 + kt2) * 64 + n + 16 * q2) * 8 + j2] = (f16)acc[q][r];
            }
        }
    }
}

extern "C" __global__ void __launch_bounds__(256)
k_scan1(const int* __restrict__ counts, int* __restrict__ bsum) {
    __shared__ int s[256];
    int t = threadIdx.x;
    int i = blockIdx.x * 256 + t;
    s[t] = (i < Nn) ? counts[i] : 0;
    __syncthreads();
    for (int d = 128; d > 0; d >>= 1) {
        if (t < d) s[t] += s[t + d];
        __syncthreads();
    }
    if (t == 0) bsum[blockIdx.x] = s[0];
}

// scan3 with fused scan2: each block reduces bsum[0..bid) itself (<=391 ints)
extern "C" __global__ void __launch_bounds__(256)
k_scan3(const int* __restrict__ counts, const int* __restrict__ bsum,
        int* __restrict__ offsets) {
    __shared__ int s[256];
    __shared__ int basev;
    int t = threadIdx.x;
    int i = blockIdx.x * 256 + t;
    int partial = 0;
    for (int k = t; k < blockIdx.x; k += 256) partial += bsum[k];
    s[t] = partial;
    __syncthreads();
    for (int d = 128; d > 0; d >>= 1) {
        if (t < d) s[t] += s[t + d];
        __syncthreads();
    }
    if (t == 0) basev = s[0];
    __syncthreads();
    int v = (i < Nn) ? counts[i] : 0;
    s[t] = v;
    __syncthreads();
    for (int d = 1; d < 256; d <<= 1) {
        int x = (t >= d) ? s[t - d] : 0;
        __syncthreads();
        s[t] += x;
        __syncthreads();
    }
    if (i < Nn) offsets[i] = basev + s[t] - v;
    if (i == 0) offsets[Nn] = Ee;
}

// pass 2: atomic-free scatter using precomputed ranks (plain store: bucket
// is re-read by the fused mlp soon -> keep it cache-resident).
extern "C" __global__ void __launch_bounds__(256)
k_scatter2(const int* __restrict__ ei, const int* __restrict__ offsets,
           const int* __restrict__ rank, int* __restrict__ bucket) {
    int e = blockIdx.x * 256 + threadIdx.x;
    int dst = ei[Ee + e];
    bucket[offsets[dst] + rank[e]] = ei[e];
}

// ---------------------------------------------------------------------------
// Fused gather + MLP(steps 5-9). 32 nodes/block, 4 waves.
// Phase 1: each wave gather-means 8 nodes (quarter-wave per edge slot,
//   bucket segment preloaded + __shfl) into LDS hraw, A-frag packed
//   block-local layout: hraw[((lnt*4+kt)*64 + m + 16*q2)*8 + j], lnt=ln>>4.
// Phase 2: steps 5-9 as before, step5 A-frags from LDS hraw.
// Removes the 51MB harawp global roundtrip + one launch; gather latency of
// one block overlaps MFMA of others. LDS 24KB. launch_bounds(256,5):
// VGPR cap 102 >= ~70 needed (no u[16] here), 5 blocks/CU.
// Tripwire: WRITE_SIZE must stay ~15.6MB (logits only); higher = spill.
// ---------------------------------------------------------------------------
extern "C" __global__ void __launch_bounds__(256, 5)
linkx_mlp(const int* __restrict__ offsets, const int* __restrict__ bucket,
          const f16* __restrict__ embh, const f16* __restrict__ hxp,
          const f16* __restrict__ wa1p, const float* __restrict__ ba1,
          const f16* __restrict__ wa2p, const float* __restrict__ ba2,
          const f16* __restrict__ ww1p, const float* __restrict__ bw1,
          const f16* __restrict__ wcp, const float* __restrict__ bc,
          float* __restrict__ out) {
    __shared__ __align__(16) f16 hraw[4096];  // gathered means, A-frag (8KB)
    __shared__ __align__(16) f16 shr[4096];   // t2p / h2p (8KB shared)
    __shared__ __align__(16) f16 hap[4096];   // ha packed (8KB)

    const int t = threadIdx.x;
    const int node0 = blockIdx.x * 32;
    const int lane = t & 63;
    const int wid = t >> 6;
    const int mt = wid >> 1;
    const int fh = wid & 1;
    const int gntb = (node0 >> 4) + mt;

    // ---- phase 1: gather-mean 8 nodes per wave into LDS ----
    {
        int q = lane >> 4;          // quarter-wave: edge slot
        int cl = (lane & 15) * 8;   // column base
#pragma unroll 1
        for (int i = 0; i < 8; i++) {
            int ln = wid * 8 + i;            // local node 0..31
            int node = node0 + ln;
            int beg = offsets[node];
            int end = offsets[node + 1];
            int deg = end - beg;
            int myidx = (lane < deg) ? bucket[beg + lane] : 0;

            float s[8];
#pragma unroll
            for (int j = 0; j < 8; j++) s[j] = 0.f;

            int dlim = (deg < 64) ? deg : 64;
            int e = q;
            for (; e + 4 < dlim; e += 8) {   // 2 row-gathers in flight
                int a0 = __shfl(myidx, e);
                int a1 = __shfl(myidx, e + 4);
                f16x8 v0 = *(const f16x8*)(embh + (size_t)a0 * HD + cl);
                f16x8 v1 = *(const f16x8*)(embh + (size_t)a1 * HD + cl);
#pragma unroll
                for (int j = 0; j < 8; j++) s[j] += (float)v0[j] + (float)v1[j];
            }
            if (e < dlim) {
                int a0 = __shfl(myidx, e);
                f16x8 v0 = *(const f16x8*)(embh + (size_t)a0 * HD + cl);
#pragma unroll
                for (int j = 0; j < 8; j++) s[j] += (float)v0[j];
            }
            for (int ii = beg + 64 + q; ii < end; ii += 4) {  // rare deg>64
                int a0 = bucket[ii];
                f16x8 v0 = *(const f16x8*)(embh + (size_t)a0 * HD + cl);
#pragma unroll
                for (int j = 0; j < 8; j++) s[j] += (float)v0[j];
            }
#pragma unroll
            for (int j = 0; j < 8; j++) {
                s[j] += __shfl_down(s[j], 32);
                s[j] += __shfl_down(s[j], 16);
            }
            if (lane < 16) {
                float inv = 1.0f / fmaxf((float)deg, 1.0f);
                f16x8 h;
#pragma unroll
                for (int j = 0; j < 8; j++) h[j] = (f16)(s[j] * inv);
                int lnt = ln >> 4, m = ln & 15;
                int kt = lane >> 2, q2 = lane & 3;
                *(f16x8*)(hraw + (((lnt * 4 + kt) * 64 + m + 16 * q2) * 8)) = h;
            }
        }
    }
    __syncthreads();

    f32x4 acc[4];
    float rreg[4][4];

    // hx residual: 16 scalar f16 loads (L2/L3-hot), issued early
    f16 hxr[4][4];
#pragma unroll
    for (int q = 0; q < 4; q++) {
        int f = (fh * 4 + q) * 16 + (lane & 15);
        int kt2 = f >> 5, q2 = (f >> 3) & 3, j2 = f & 7;
#pragma unroll
        for (int r = 0; r < 4; r++) {
            int n = (lane >> 4) * 4 + r;
            hxr[q][r] = hxp[((gntb * 4 + kt2) * 64 + n + 16 * q2) * 8 + j2];
        }
    }

    // step5: t2 = relu(hraw @ wa1 + ba1); A from LDS
    INIT_ACC(ba1)
    GEMM_K128(hraw, wa1p)
    EPILOGUE(0, shr)          // t2p
    __syncthreads();

    // rreg = hx
#pragma unroll
    for (int q = 0; q < 4; q++)
#pragma unroll
        for (int r = 0; r < 4; r++) rreg[q][r] = (float)hxr[q][r];

    // step6: ha = t2 @ wa2 + ba2 -> hap, rreg += ha
    INIT_ACC(ba2)
    GEMM_K128(shr, wa2p)
    EPILOGUE(2, hap)
    __syncthreads();          // t2p reads done -> shr reusable

    // step7+8: h2 = relu(relu([hx|ha] @ ww1 + bw1) + hx + ha) -> h2p
    INIT_ACC(bw1)
#pragma unroll
    for (int kt = 0; kt < 4; kt++) {   // hx half from GLOBAL hxp (coalesced)
        f16x8 a = *(const f16x8*)(hxp + ((gntb * 4 + kt) * 64 + lane) * 8);
#pragma unroll
        for (int q = 0; q < 4; q++) {
            f16x8 b = *(const f16x8*)(ww1p + (((fh*4+q)*8 + kt)*64 + lane)*8);
            acc[q] = __builtin_amdgcn_mfma_f32_16x16x32_f16(a, b, acc[q], 0, 0, 0);
        }
    }
#pragma unroll
    for (int kt = 4; kt < 8; kt++) {   // ha half from LDS
        f16x8 a = *(const f16x8*)(hap + ((mt * 4 + (kt - 4)) * 64 + lane) * 8);
#pragma unroll
        for (int q = 0; q < 4; q++) {
            f16x8 b = *(const f16x8*)(ww1p + (((fh*4+q)*8 + kt)*64 + lane)*8);
            acc[q] = __builtin_amdgcn_mfma_f32_16x16x32_f16(a, b, acc[q], 0, 0, 0);
        }
    }
    EPILOGUE(3, shr)          // h2p
    __syncthreads();

    // step9: logits = h2 @ wc + bc (3 ftiles: fh0 -> {0,2}, fh1 -> {1})
    {
        int nft = (fh == 0) ? 2 : 1;
#pragma unroll 2
        for (int ii = 0; ii < nft; ii++) {
            int ft = (ii == 0) ? fh : 2;
            int f = ft * 16 + (lane & 15);
            f32x4 c;
            float bv = (f < NCLS) ? bc[f] : 0.f;
            c[0] = bv; c[1] = bv; c[2] = bv; c[3] = bv;
#pragma unroll
            for (int kt = 0; kt < 4; kt++) {
                f16x8 a = *(const f16x8*)(shr + ((mt * 4 + kt) * 64 + lane) * 8);
                f16x8 b = *(const f16x8*)(wcp + ((ft * 4 + kt) * 64 + lane) * 8);
                c = __builtin_amdgcn_mfma_f32_16x16x32_f16(a, b, c, 0, 0, 0);
            }
            if (f < NCLS) {
#pragma unroll
                for (int r = 0; r < 4; r++) {
                    int n = node0 + mt * 16 + (lane >> 4) * 4 + r;
                    out[(size_t)n * NCLS + f] = c[r];
                }
            }
        }
    }
}

extern "C" void kernel_launch(void* const* d_in, const int* in_sizes, int n_in,
                              void* d_out, int out_size, void* d_ws, size_t ws_size,
                              hipStream_t stream) {
    const float* x   = (const float*)d_in[0];
    const int*   ei  = (const int*)d_in[1];
    const float* emb = (const float*)d_in[2];
    const float* wx1 = (const float*)d_in[3];
    const float* bx1 = (const float*)d_in[4];
    const float* wx2 = (const float*)d_in[5];
    const float* bx2 = (const float*)d_in[6];
    const float* wa1 = (const float*)d_in[7];
    const float* ba1 = (const float*)d_in[8];
    const float* wa2 = (const float*)d_in[9];
    const float* ba2 = (const float*)d_in[10];
    const float* ww1 = (const float*)d_in[11];
    const float* bw1 = (const float*)d_in[12];
    const float* wc  = (const float*)d_in[13];
    const float* bc  = (const float*)d_in[14];
    float* out = (float*)d_out;

    int* ws = (int*)d_ws;
    int* counts  = ws;                 // [Nn]  (atomic rank allocator)
    int* offsets = ws + 2 * Nn;        // [Nn+1]
    int* bsum    = ws + 3 * Nn + 16;   // [NBLK]
    int* bucket  = ws + 3 * Nn + 512;  // [Ee]
    f16* wp      = (f16*)(ws + 3 * Nn + 512 + Ee);  // 120832 f16 (16B aligned)
    f16* wx1p = wp;                 // 32768
    f16* wx2p = wp + 32768;         // 16384
    f16* wa1p = wp + 49152;         // 16384
    f16* wa2p = wp + 65536;         // 16384
    f16* ww1p = wp + 81920;         // 32768
    f16* wcp  = wp + 114688;        // 6144
    // rank[Ee] occupies the region formerly used by harawp (dead layout slot)
    int* rank   = (int*)(wp + 131072);               // [Ee]
    f16* embh   = wp + 131072 + (size_t)Nn * HD;     // [Nn*HD] f16, linear
    f16* hxp    = embh + (size_t)Nn * HD;            // [Nn*HD] f16, A-packed

    hipMemsetAsync(ws, 0, (size_t)Nn * sizeof(int), stream);

    k_wpack<<<472, 256, 0, stream>>>(wx1, wx2, wa1, wa2, ww1, wc, wp);
    // 10938 blocks = interleaved [1 hist | 4 emb | 2 hx] groups of 7
    k_prep<<<10938, 256, 0, stream>>>(ei, counts, rank, emb, embh,
                                      x, wx1p, bx1, wx2p, bx2, hxp);
    k_scan1<<<NBLK, 256, 0, stream>>>(counts, bsum);
    k_scan3<<<NBLK, 256, 0, stream>>>(counts, bsum, offsets);
    k_scatter2<<<Ee / 256, 256, 0, stream>>>(ei, offsets, rank, bucket);

    linkx_mlp<<<Nn / 32, 256, 0, stream>>>(offsets, bucket, embh, hxp,
                                           wa1p, ba1, wa2p, ba2,
                                           ww1p, bw1, wcp, bc, out);
}